// Round 11
// baseline (427.478 us; speedup 1.0000x reference)
//
#include <hip/hip_runtime.h>
#include <math.h>

#define N_NODES 100000
#define N_EDGES 3200000
#define N_FEAT  500
#define N_HID   16
#define N_CLS   7

#define BKT_SHIFT 7
#define BKT_SIZE  128
#define NBKT      782            // ceil(100000/128)
#define NBLK_BIN  256            // edge-chunk blocks for binpass
#define EDGES_PER_BLK 12500      // 256 * 12500 = 3.2M exactly
#define SLOT      64             // entries per (bucket, block) cell: mean 16 + 12 sd
#define SORT_SLOT 6144           // sorted entries per bucket (max ~4500)
#define SBUF_CAP  5632           // max edges/bucket (mean 4092, sd 64 -> 24 sd)

// ---------------- workspace layout (dword offsets) --------------------------
#define OFF_DINV   0            // 100000 f
#define OFF_LENS   100000       // 200192 i : lens[bucket*256 + block]
#define OFF_ROWP   300192       // 100008 i : END pointers (base b*SORT_SLOT)
#define OFF_WP     400200       // 8192 dwords packed W1
#define OFF_M1S    408392       // 800000 dwords = 1.6M ushort bf16 (m1*dinv)
#define OFF_M2S    1208392      // 400000 dwords = 800K ushort bf16 (m2*dinv)
#define OFF_SORTED 1608392      // 782*6144 = 4804608 u32
#define OFF_BINNED 6413000      // 782*256*64 = 12812288 u32 (sparse slots)
// total 19,225,288 dwords ~= 77 MB

typedef __attribute__((ext_vector_type(8))) short short8v;
typedef __attribute__((ext_vector_type(4))) float f32x4v;

// ------------------------------------------------------------- bf16 helpers
__device__ inline unsigned short f2bf(float f) {
    unsigned int u = __float_as_uint(f);
    return (unsigned short)((u + 0x7FFF + ((u >> 16) & 1)) >> 16);
}
__device__ inline float bf2f(unsigned short h) {
    return __uint_as_float((unsigned int)h << 16);
}

// ------------------------------------------- W1 fragment pre-pack (hi/lo bf16)
__global__ void wpack(const float* __restrict__ W1, uint4* __restrict__ wp) {
    int p = threadIdx.x;
    int s = p >> 6, l = p & 63;
    int col = l & 15, kb = s * 32 + (l >> 4) * 8;
    unsigned int hw[4], lw[4];
#pragma unroll
    for (int d = 0; d < 4; ++d) {
        unsigned int hpair = 0, lpair = 0;
#pragma unroll
        for (int e = 0; e < 2; ++e) {
            int k = kb + d * 2 + e;
            float w0 = (k < N_FEAT) ? W1[k * 16 + col] : 0.f;
            unsigned int u = __float_as_uint(w0);
            unsigned int uh = u & 0xFFFF0000u;        // hi = truncated bf16
            float res = w0 - __uint_as_float(uh);     // exact residual
            hpair |= (uh >> 16) << (16 * e);
            lpair |= (unsigned int)f2bf(res) << (16 * e);
        }
        hw[d] = hpair; lw[d] = lpair;
    }
    wp[p] = make_uint4(hw[0], hw[1], hw[2], hw[3]);
    wp[1024 + p] = make_uint4(lw[0], lw[1], lw[2], lw[3]);
}

// ---------------- single-pass binning into per-(bucket,block) slots.
// No hist/scan needed: block-private LDS cursors from 0; slots are
// block-exclusive (no cross-block/XCD line sharing). lens[] records fill.
__global__ __launch_bounds__(1024) void binpass(const int* __restrict__ src,
                        const int* __restrict__ dst,
                        unsigned int* __restrict__ binned, int* __restrict__ lens) {
    __shared__ int cur[NBKT];
    int t = threadIdx.x, b = blockIdx.x;
    for (int i = t; i < NBKT; i += 1024) cur[i] = 0;
    __syncthreads();
    const int4* s4 = (const int4*)(src + b * EDGES_PER_BLK);
    const int4* d4 = (const int4*)(dst + b * EDGES_PER_BLK);
    for (int k = t; k < EDGES_PER_BLK / 4; k += 1024) {
        int4 d = d4[k];
        int4 s = s4[k];
        int bk, pos;
        bk = d.x >> BKT_SHIFT; pos = atomicAdd(&cur[bk], 1);
        if (pos < SLOT) binned[(bk * NBLK_BIN + b) * SLOT + pos] =
            (unsigned int)s.x | ((unsigned int)(d.x & (BKT_SIZE - 1)) << 17);
        bk = d.y >> BKT_SHIFT; pos = atomicAdd(&cur[bk], 1);
        if (pos < SLOT) binned[(bk * NBLK_BIN + b) * SLOT + pos] =
            (unsigned int)s.y | ((unsigned int)(d.y & (BKT_SIZE - 1)) << 17);
        bk = d.z >> BKT_SHIFT; pos = atomicAdd(&cur[bk], 1);
        if (pos < SLOT) binned[(bk * NBLK_BIN + b) * SLOT + pos] =
            (unsigned int)s.z | ((unsigned int)(d.z & (BKT_SIZE - 1)) << 17);
        bk = d.w >> BKT_SHIFT; pos = atomicAdd(&cur[bk], 1);
        if (pos < SLOT) binned[(bk * NBLK_BIN + b) * SLOT + pos] =
            (unsigned int)s.w | ((unsigned int)(d.w & (BKT_SIZE - 1)) << 17);
    }
    __syncthreads();
    for (int i = t; i < NBKT; i += 1024) lens[i * NBLK_BIN + b] = cur[i];
}

// ---------------- per-node histogram -> rowp (END ptrs, base b*SORT_SLOT) + dinv.
// Wave-per-segment reads: lane i reads entry i of a 64-entry slot (coalesced,
// only valid bytes touched).
__global__ __launch_bounds__(512) void sortA(const unsigned int* __restrict__ binned,
        const int* __restrict__ lens, int* __restrict__ rowp,
        float* __restrict__ dinv) {
    __shared__ int cnt[BKT_SIZE];
    __shared__ int sc[BKT_SIZE];
    __shared__ int sl[NBLK_BIN];
    int t = threadIdx.x, b = blockIdx.x;
    int lane = t & 63, w = t >> 6;
    if (t < BKT_SIZE) cnt[t] = 0;
    if (t < NBLK_BIN) sl[t] = lens[b * NBLK_BIN + t];
    __syncthreads();
    for (int seg = w; seg < NBLK_BIN; seg += 8) {
        int len = sl[seg];
        if (lane < len) {
            unsigned int u = binned[(b * NBLK_BIN + seg) * SLOT + lane];
            atomicAdd(&cnt[(u >> 17) & (BKT_SIZE - 1)], 1);
        }
    }
    __syncthreads();
    int v = (t < BKT_SIZE) ? cnt[t] : 0;
    if (t < BKT_SIZE) sc[t] = v;
    __syncthreads();
    for (int off = 1; off < BKT_SIZE; off <<= 1) {
        int a = (t < BKT_SIZE && t >= off) ? sc[t - off] : 0;
        __syncthreads();
        if (t < BKT_SIZE) sc[t] += a;
        __syncthreads();
    }
    if (t < BKT_SIZE) {
        int g = b * BKT_SIZE + t;
        if (g < N_NODES) {
            rowp[g] = b * SORT_SLOT + sc[t];      // END pointer (inclusive prefix)
            dinv[g] = rsqrtf((float)v + 1.0f);    // +1 self loop
        }
    }
}

// ------------------------------------------- m1s = bf16((x @ W1) * dinv)
// MFMA, W1 frags in LDS, register ring distance-6 A prefetch, no in-loop
// barriers (R9/R10 structure, verified).
#define G1_NBLK 1563   // ceil(100000/64)

__device__ inline void split8(const float4 a, const float4 b, short8v& hi, short8v& lo) {
    float f[8] = {a.x, a.y, a.z, a.w, b.x, b.y, b.z, b.w};
#pragma unroll
    for (int i = 0; i < 8; ++i) {
        unsigned int u = __float_as_uint(f[i]);
        unsigned int uh = u & 0xFFFF0000u;
        hi[i] = (short)(u >> 16);
        lo[i] = (short)f2bf(f[i] - __uint_as_float(uh));
    }
}

__global__ __launch_bounds__(256) void gemm1(const float* __restrict__ x,
        const uint4* __restrict__ wp, const float* __restrict__ dinv,
        unsigned short* __restrict__ m1s) {
    __shared__ uint4 swp[2048];   // 32 KB: all W1 frags (hi 0..1023, lo 1024..2047)
    const int t = threadIdx.x, b = blockIdx.x;
    const int lane = t & 63, w = t >> 6;
#pragma unroll
    for (int i = 0; i < 8; ++i) swp[i * 256 + t] = wp[i * 256 + t];
    __syncthreads();

    const int r16 = lane & 15, g = lane >> 4;
    const int rowbase = b * 64 + w * 16;
    const int row = rowbase + r16;
    const int srow = (row < N_NODES) ? row : 0;
    const float* pA = x + (size_t)srow * N_FEAT + g * 8;
    // tail step 15 (k=480..511): load valid iff last float < 500; else x[0] (B=0 there)
    const float* t0 = (g <= 2) ? pA + 480 : x;
    const float* t1 = (g <= 1) ? pA + 484 : x;

    // register ring, distance-6 prefetch (named slots, compile-time indices)
    float4 a0_0 = *(const float4*)(pA);        float4 a1_0 = *(const float4*)(pA + 4);
    float4 a0_1 = *(const float4*)(pA + 32);   float4 a1_1 = *(const float4*)(pA + 36);
    float4 a0_2 = *(const float4*)(pA + 64);   float4 a1_2 = *(const float4*)(pA + 68);
    float4 a0_3 = *(const float4*)(pA + 96);   float4 a1_3 = *(const float4*)(pA + 100);
    float4 a0_4 = *(const float4*)(pA + 128);  float4 a1_4 = *(const float4*)(pA + 132);
    float4 a0_5 = *(const float4*)(pA + 160);  float4 a1_5 = *(const float4*)(pA + 164);

    f32x4v acc = {0.f, 0.f, 0.f, 0.f};
#pragma unroll
    for (int s = 0; s < 16; ++s) {
        float4 xa, xb;
        switch (s % 6) {
            case 0: xa = a0_0; xb = a1_0; break;
            case 1: xa = a0_1; xb = a1_1; break;
            case 2: xa = a0_2; xb = a1_2; break;
            case 3: xa = a0_3; xb = a1_3; break;
            case 4: xa = a0_4; xb = a1_4; break;
            default: xa = a0_5; xb = a1_5; break;
        }
        if (s <= 9) {   // prefetch step s+6 into the slot just consumed
            int tg = s + 6;
            const float* p = (tg == 15) ? t0 : pA + tg * 32;
            const float* q = (tg == 15) ? t1 : pA + tg * 32 + 4;
            float4 n0 = *(const float4*)p;
            float4 n1 = *(const float4*)q;
            switch (s % 6) {
                case 0: a0_0 = n0; a1_0 = n1; break;
                case 1: a0_1 = n0; a1_1 = n1; break;
                case 2: a0_2 = n0; a1_2 = n1; break;
                case 3: a0_3 = n0; a1_3 = n1; break;
                case 4: a0_4 = n0; a1_4 = n1; break;
                default: a0_5 = n0; a1_5 = n1; break;
            }
        }
        short8v ah, al;
        split8(xa, xb, ah, al);
        short8v bh = *reinterpret_cast<const short8v*>(&swp[s * 64 + lane]);
        short8v bl = *reinterpret_cast<const short8v*>(&swp[1024 + s * 64 + lane]);
        acc = __builtin_amdgcn_mfma_f32_16x16x32_bf16(ah, bh, acc, 0, 0, 0);
        acc = __builtin_amdgcn_mfma_f32_16x16x32_bf16(al, bh, acc, 0, 0, 0);
        acc = __builtin_amdgcn_mfma_f32_16x16x32_bf16(ah, bl, acc, 0, 0, 0);
    }

    // C/D layout: col = lane&15, row = (lane>>4)*4 + j
#pragma unroll
    for (int j = 0; j < 4; ++j) {
        int r = rowbase + g * 4 + j;
        if (r < N_NODES) m1s[(size_t)r * 16 + r16] = f2bf(acc[j] * dinv[r]);
    }
}

// ---------------- scatter slots -> sbuf (node-grouped) -> write sorted
// -> FUSED layer-1 aggregate from sbuf + bias + ReLU + h@W2 -> m2s.
__global__ __launch_bounds__(512) void sortAgg1(const unsigned int* __restrict__ binned,
        const int* __restrict__ lens, const int* __restrict__ rowp,
        const float* __restrict__ dinv,
        const unsigned short* __restrict__ m1s, const float* __restrict__ b1,
        const float* __restrict__ W2, unsigned int* __restrict__ sorted,
        unsigned short* __restrict__ m2s) {
    __shared__ unsigned int sbuf[SBUF_CAP];
    __shared__ int cur[BKT_SIZE];
    __shared__ int sl[NBLK_BIN];
    __shared__ float acc[BKT_SIZE * 17];
    __shared__ float sW2[N_HID * N_CLS];
    __shared__ float sb1[N_HID];
    int t = threadIdx.x, b = blockIdx.x;
    int lane = t & 63, w = t >> 6;
    const int base = b * SORT_SLOT;
    if (t < N_HID * N_CLS) sW2[t] = W2[t];
    if (t < N_HID) sb1[t] = b1[t];
    if (t < NBLK_BIN) sl[t] = lens[b * NBLK_BIN + t];
    if (t < BKT_SIZE) {
        int g = b * BKT_SIZE + t;
        cur[t] = (g < N_NODES && t > 0) ? rowp[g - 1] - base : 0;   // local begin
    }
    __syncthreads();
    for (int seg = w; seg < NBLK_BIN; seg += 8) {
        int len = sl[seg];
        if (lane < len) {
            unsigned int u = binned[(b * NBLK_BIN + seg) * SLOT + lane];
            int pos = atomicAdd(&cur[(u >> 17) & (BKT_SIZE - 1)], 1);
            if (pos < SBUF_CAP) sbuf[pos] = u & 0x1FFFF;
        }
    }
    __syncthreads();
    int lastg = b * BKT_SIZE + BKT_SIZE - 1;
    if (lastg >= N_NODES) lastg = N_NODES - 1;
    int total = rowp[lastg] - base;
    for (int i = t; i < total; i += 512) sorted[base + i] = sbuf[i];
    // ---- aggregate straight from sbuf (edge list stays in LDS)
    {
        int nn = t >> 2, q = t & 3;
        int g = b * BKT_SIZE + nn;
        float a0 = 0.f, a1 = 0.f, a2 = 0.f, a3 = 0.f;
        if (g < N_NODES) {
            int lbeg = (nn > 0) ? rowp[g - 1] - base : 0;
            int lend = rowp[g] - base;
            int p = lbeg;
            for (; p + 3 < lend; p += 4) {
                unsigned int s0 = sbuf[p], s1 = sbuf[p + 1];
                unsigned int s2 = sbuf[p + 2], s3 = sbuf[p + 3];
                uint2 w0 = *(const uint2*)&m1s[(size_t)s0 * 16 + q * 4];
                uint2 w1 = *(const uint2*)&m1s[(size_t)s1 * 16 + q * 4];
                uint2 w2 = *(const uint2*)&m1s[(size_t)s2 * 16 + q * 4];
                uint2 w3 = *(const uint2*)&m1s[(size_t)s3 * 16 + q * 4];
                a0 += __uint_as_float(w0.x << 16);
                a1 += __uint_as_float(w0.x & 0xFFFF0000u);
                a2 += __uint_as_float(w0.y << 16);
                a3 += __uint_as_float(w0.y & 0xFFFF0000u);
                a0 += __uint_as_float(w1.x << 16);
                a1 += __uint_as_float(w1.x & 0xFFFF0000u);
                a2 += __uint_as_float(w1.y << 16);
                a3 += __uint_as_float(w1.y & 0xFFFF0000u);
                a0 += __uint_as_float(w2.x << 16);
                a1 += __uint_as_float(w2.x & 0xFFFF0000u);
                a2 += __uint_as_float(w2.y << 16);
                a3 += __uint_as_float(w2.y & 0xFFFF0000u);
                a0 += __uint_as_float(w3.x << 16);
                a1 += __uint_as_float(w3.x & 0xFFFF0000u);
                a2 += __uint_as_float(w3.y << 16);
                a3 += __uint_as_float(w3.y & 0xFFFF0000u);
            }
            for (; p < lend; ++p) {
                unsigned int s0 = sbuf[p];
                uint2 w0 = *(const uint2*)&m1s[(size_t)s0 * 16 + q * 4];
                a0 += __uint_as_float(w0.x << 16);
                a1 += __uint_as_float(w0.x & 0xFFFF0000u);
                a2 += __uint_as_float(w0.y << 16);
                a3 += __uint_as_float(w0.y & 0xFFFF0000u);
            }
        }
        __syncthreads();
        float* ap = &acc[nn * 17 + q * 4];
        ap[0] = a0; ap[1] = a1; ap[2] = a2; ap[3] = a3;
    }
    __syncthreads();
    // h = relu(dinv_g * (acc + m1s_g) + b1), in place (stride 17)
    for (int idx = t; idx < BKT_SIZE * 16; idx += 512) {
        int nn = idx >> 4, jj = idx & 15;
        int gg = b * BKT_SIZE + nn;
        if (gg < N_NODES) {
            float di = dinv[gg];
            float hv = di * (acc[nn * 17 + jj] + bf2f(m1s[(size_t)gg * 16 + jj])) + sb1[jj];
            acc[nn * 17 + jj] = hv > 0.f ? hv : 0.f;
        }
    }
    __syncthreads();
    // m2s = bf16(dinv_g * (h @ W2)), stride 8, slot 7 = 0 pad
    for (int idx = t; idx < BKT_SIZE * 8; idx += 512) {
        int nn = idx >> 3, cc = idx & 7;
        int gg = b * BKT_SIZE + nn;
        if (gg < N_NODES) {
            float sum = 0.f;
            if (cc < N_CLS) {
#pragma unroll
                for (int jj = 0; jj < N_HID; ++jj) sum += acc[nn * 17 + jj] * sW2[jj * 7 + cc];
                sum *= dinv[gg];
            }
            m2s[(size_t)gg * 8 + cc] = f2bf(sum);
        }
    }
}

// -------- layer-2 aggregate + bias + log-softmax. 512 thr: 4 lanes/node,
// lane q owns slots 2q..2q+1 (uint loads); walk unrolled 4-deep.
__global__ __launch_bounds__(512) void agg2(const unsigned int* __restrict__ sorted,
        const int* __restrict__ rowp, const float* __restrict__ dinv,
        const unsigned short* __restrict__ m2s, const float* __restrict__ b2,
        float* __restrict__ out) {
    __shared__ float acc[BKT_SIZE * 9];
    int t = threadIdx.x, b = blockIdx.x;
    int n = t >> 2, q = t & 3;
    int g = b * BKT_SIZE + n;
    float a0 = 0.f, a1 = 0.f;
    if (g < N_NODES) {
        int beg = (n > 0) ? rowp[g - 1] : b * SORT_SLOT;
        int end = rowp[g];
        int p = beg;
        for (; p + 3 < end; p += 4) {
            unsigned int s0 = sorted[p], s1 = sorted[p + 1];
            unsigned int s2 = sorted[p + 2], s3 = sorted[p + 3];
            unsigned int w0 = *(const unsigned int*)&m2s[(size_t)s0 * 8 + q * 2];
            unsigned int w1 = *(const unsigned int*)&m2s[(size_t)s1 * 8 + q * 2];
            unsigned int w2 = *(const unsigned int*)&m2s[(size_t)s2 * 8 + q * 2];
            unsigned int w3 = *(const unsigned int*)&m2s[(size_t)s3 * 8 + q * 2];
            a0 += __uint_as_float(w0 << 16); a1 += __uint_as_float(w0 & 0xFFFF0000u);
            a0 += __uint_as_float(w1 << 16); a1 += __uint_as_float(w1 & 0xFFFF0000u);
            a0 += __uint_as_float(w2 << 16); a1 += __uint_as_float(w2 & 0xFFFF0000u);
            a0 += __uint_as_float(w3 << 16); a1 += __uint_as_float(w3 & 0xFFFF0000u);
        }
        for (; p < end; ++p) {
            unsigned int s0 = sorted[p];
            unsigned int w0 = *(const unsigned int*)&m2s[(size_t)s0 * 8 + q * 2];
            a0 += __uint_as_float(w0 << 16); a1 += __uint_as_float(w0 & 0xFFFF0000u);
        }
    }
    float* ap = &acc[n * 9 + q * 2];
    ap[0] = a0; ap[1] = a1;
    __syncthreads();
    int j = t & 7;
    for (int pass = 0; pass < 2; ++pass) {
        int nn = (t >> 3) + pass * 64;
        int gg = b * BKT_SIZE + nn;
        bool valid = (gg < N_NODES) && (j < N_CLS);
        float v = -1e30f;
        if (valid) {
            float di = dinv[gg];
            v = di * (acc[nn * 9 + j] + bf2f(m2s[(size_t)gg * 8 + j])) + b2[j];
        }
        float mx = v;
#pragma unroll
        for (int off = 1; off < 8; off <<= 1) mx = fmaxf(mx, __shfl_xor(mx, off, 8));
        float ex = valid ? expf(v - mx) : 0.f;
        float sum = ex;
#pragma unroll
        for (int off = 1; off < 8; off <<= 1) sum += __shfl_xor(sum, off, 8);
        float ls = mx + logf(sum);
        if (valid) out[(size_t)gg * 7 + j] = v - ls;
    }
}

// ----------------------------------------------------------------
extern "C" void kernel_launch(void* const* d_in, const int* in_sizes, int n_in,
                              void* d_out, int out_size, void* d_ws, size_t ws_size,
                              hipStream_t stream) {
    const float* x  = (const float*)d_in[0];
    const int*   ei = (const int*)d_in[1];
    const float* W1 = (const float*)d_in[2];
    const float* b1 = (const float*)d_in[3];
    const float* W2 = (const float*)d_in[4];
    const float* b2 = (const float*)d_in[5];
    float* out = (float*)d_out;
    char*  wsb = (char*)d_ws;   // needs ~77 MB

    const int* src = ei;               // edge_index[0]
    const int* dst = ei + N_EDGES;     // edge_index[1]

    float*          dinv   = (float*)wsb + OFF_DINV;
    int*            lens   = (int*)wsb + OFF_LENS;
    int*            rowp   = (int*)wsb + OFF_ROWP;
    uint4*          wp     = (uint4*)((int*)wsb + OFF_WP);
    unsigned short* m1s    = (unsigned short*)(wsb + (size_t)OFF_M1S * 4);
    unsigned short* m2s    = (unsigned short*)(wsb + (size_t)OFF_M2S * 4);
    unsigned int*   sorted = (unsigned int*)wsb + OFF_SORTED;
    unsigned int*   binned = (unsigned int*)wsb + OFF_BINNED;

    wpack    <<<1, 1024, 0, stream>>>(W1, wp);
    binpass  <<<NBLK_BIN, 1024, 0, stream>>>(src, dst, binned, lens);
    sortA    <<<NBKT, 512, 0, stream>>>(binned, lens, rowp, dinv);
    gemm1    <<<G1_NBLK, 256, 0, stream>>>(x, wp, dinv, m1s);
    sortAgg1 <<<NBKT, 512, 0, stream>>>(binned, lens, rowp, dinv,
                                        m1s, b1, W2, sorted, m2s);
    agg2     <<<NBKT, 512, 0, stream>>>(sorted, rowp, dinv, m2s, b2, out);
}

// Round 12
// 418.180 us; speedup vs baseline: 1.0222x; 1.0222x over previous
//
#include <hip/hip_runtime.h>
#include <math.h>

#define N_NODES 100000
#define N_EDGES 3200000
#define N_FEAT  500
#define N_HID   16
#define N_CLS   7

#define BKT_SHIFT 7
#define BKT_SIZE  128
#define NBKT      782            // ceil(100000/128)
#define NBLK_BIN  256            // edge-chunk blocks for hist/binpass
#define EDGES_PER_BLK 12500      // 256 * 12500 = 3.2M exactly
#define COUNTS_LEN (NBKT * NBLK_BIN)   // 200192
#define NBLK_SCANA NBKT          // scanA: one block per bucket
#define SBUF_CAP  5632           // max edges/bucket (mean 4092, sd 64 -> 24 sd)

// ---------------- workspace layout (dword offsets) --------------------------
// counts layout: C[block][bucket] = counts[block*NBKT + bucket]  (TRANSPOSED:
// hist writes coalesced, binpass reads contiguous; scanA reads strided in L2)
#define OFF_DINV   0            // 100000 f
#define OFF_COUNTS 100000       // 200192 i
#define OFF_BSUM   300192       // 1024 i
#define OFF_ROWP   301216       // 100001 i (+3 pad)
#define OFF_BINNED 401220       // 3200000 u32 (src | dst_local<<17)
#define OFF_SORTED 3601220      // 3200000 u32 (src, grouped per dst node)
#define OFF_WP     6801220      // 8192 dwords packed W1
#define OFF_M1S    6809412      // 800000 dwords = 1.6M ushort bf16 (m1*dinv)
#define OFF_M2S    7609412      // 400000 dwords = 800K ushort bf16 (m2*dinv)
// total ~32.0 MB

typedef __attribute__((ext_vector_type(8))) short short8v;
typedef __attribute__((ext_vector_type(4))) float f32x4v;

// ------------------------------------------------------------- bf16 helpers
__device__ inline unsigned short f2bf(float f) {
    unsigned int u = __float_as_uint(f);
    return (unsigned short)((u + 0x7FFF + ((u >> 16) & 1)) >> 16);
}
__device__ inline float bf2f(unsigned short h) {
    return __uint_as_float((unsigned int)h << 16);
}

// ------------------------------------------------------------- pass 1: hist
// 1024 thr + 4-way replicated counters; transposed coalesced output write.
__global__ __launch_bounds__(1024) void hist(const int* __restrict__ dst,
                                             int* __restrict__ counts) {
    __shared__ int cnt[4][NBKT];
    int t = threadIdx.x, b = blockIdx.x;
    int wq = (t >> 6) & 3;
    for (int i = t; i < 4 * NBKT; i += 1024) ((int*)cnt)[i] = 0;
    __syncthreads();
    const int4* d4 = (const int4*)(dst + b * EDGES_PER_BLK);
    for (int k = t; k < EDGES_PER_BLK / 4; k += 1024) {
        int4 d = d4[k];
        atomicAdd(&cnt[wq][d.x >> BKT_SHIFT], 1);
        atomicAdd(&cnt[wq][d.y >> BKT_SHIFT], 1);
        atomicAdd(&cnt[wq][d.z >> BKT_SHIFT], 1);
        atomicAdd(&cnt[wq][d.w >> BKT_SHIFT], 1);
    }
    __syncthreads();
    for (int i = t; i < NBKT; i += 1024)
        counts[b * NBKT + i] = cnt[0][i] + cnt[1][i] + cnt[2][i] + cnt[3][i];
}

// ---------------- scanA: block k scans bucket k across the 256 bin-blocks
// (strided reads of an 800KB L2-resident array; writes back exclusive prefix)
__global__ void scanA(int* __restrict__ counts, int* __restrict__ bsum) {
    __shared__ int s[256];
    int t = threadIdx.x, k = blockIdx.x;
    int v = counts[t * NBKT + k];
    s[t] = v;
    __syncthreads();
    for (int off = 1; off < 256; off <<= 1) {
        int a = (t >= off) ? s[t - off] : 0;
        __syncthreads();
        s[t] += a;
        __syncthreads();
    }
    counts[t * NBKT + k] = s[t] - v;   // exclusive within bucket k
    if (t == 255) bsum[k] = s[255];    // bucket total
}

// scanB fused with wpack (both are exactly 1024 independent threads of work)
__global__ void scanB_wpack(int* __restrict__ bsum, const float* __restrict__ W1,
                            uint4* __restrict__ wp) {
    int t = threadIdx.x;
    // ---- wpack: wp[s*64+lane] = B_hi frag (k = s*32+(lane>>4)*8+e, col=lane&15)
    {
        int p = t;
        int s = p >> 6, l = p & 63;
        int col = l & 15, kb = s * 32 + (l >> 4) * 8;
        unsigned int hw[4], lw[4];
#pragma unroll
        for (int d = 0; d < 4; ++d) {
            unsigned int hpair = 0, lpair = 0;
#pragma unroll
            for (int e = 0; e < 2; ++e) {
                int k = kb + d * 2 + e;
                float w0 = (k < N_FEAT) ? W1[k * 16 + col] : 0.f;
                unsigned int u = __float_as_uint(w0);
                unsigned int uh = u & 0xFFFF0000u;        // hi = truncated bf16
                float res = w0 - __uint_as_float(uh);     // exact residual
                hpair |= (uh >> 16) << (16 * e);
                lpair |= (unsigned int)f2bf(res) << (16 * e);
            }
            hw[d] = hpair; lw[d] = lpair;
        }
        wp[p] = make_uint4(hw[0], hw[1], hw[2], hw[3]);
        wp[1024 + p] = make_uint4(lw[0], lw[1], lw[2], lw[3]);
    }
    // ---- scanB over bsum (bucket totals -> exclusive bucket bases)
    __shared__ int s[1024];
    int v = (t < NBKT) ? bsum[t] : 0;
    s[t] = v;
    __syncthreads();
    for (int off = 1; off < 1024; off <<= 1) {
        int a = (t >= off) ? s[t - off] : 0;
        __syncthreads();
        s[t] += a;
        __syncthreads();
    }
    if (t < NBKT) bsum[t] = s[t] - v;
}

// ------------------------------------------------------------- pass 2: bin
__global__ __launch_bounds__(1024) void binpass(const int* __restrict__ src,
                        const int* __restrict__ dst,
                        const int* __restrict__ counts, const int* __restrict__ bsum,
                        unsigned int* __restrict__ binned) {
    __shared__ int cur[NBKT];
    int t = threadIdx.x, b = blockIdx.x;
    for (int i = t; i < NBKT; i += 1024) cur[i] = counts[b * NBKT + i] + bsum[i];
    __syncthreads();
    const int4* s4 = (const int4*)(src + b * EDGES_PER_BLK);
    const int4* d4 = (const int4*)(dst + b * EDGES_PER_BLK);
    for (int k = t; k < EDGES_PER_BLK / 4; k += 1024) {
        int4 d = d4[k];
        int4 s = s4[k];
        int pos;
        pos = atomicAdd(&cur[d.x >> BKT_SHIFT], 1);
        binned[pos] = (unsigned int)s.x | ((unsigned int)(d.x & (BKT_SIZE - 1)) << 17);
        pos = atomicAdd(&cur[d.y >> BKT_SHIFT], 1);
        binned[pos] = (unsigned int)s.y | ((unsigned int)(d.y & (BKT_SIZE - 1)) << 17);
        pos = atomicAdd(&cur[d.z >> BKT_SHIFT], 1);
        binned[pos] = (unsigned int)s.z | ((unsigned int)(d.z & (BKT_SIZE - 1)) << 17);
        pos = atomicAdd(&cur[d.w >> BKT_SHIFT], 1);
        binned[pos] = (unsigned int)s.w | ((unsigned int)(d.w & (BKT_SIZE - 1)) << 17);
    }
}

// ---------------- pass 3a: per-node histogram -> rowptr (begin) + dinv
// bucket b's edge range is simply [bsum[b], bsum[b+1])
__global__ __launch_bounds__(512) void sortA(const unsigned int* __restrict__ binned,
        const int* __restrict__ bsum,
        int* __restrict__ rowptr, float* __restrict__ dinv) {
    __shared__ int cnt[BKT_SIZE];
    __shared__ int sc[BKT_SIZE];
    int t = threadIdx.x, b = blockIdx.x;
    int beg = bsum[b];
    int end = (b < NBKT - 1) ? bsum[b + 1] : N_EDGES;
    if (t < BKT_SIZE) cnt[t] = 0;
    __syncthreads();
    for (int e = beg + t; e < end; e += 512)
        atomicAdd(&cnt[(binned[e] >> 17) & (BKT_SIZE - 1)], 1);
    __syncthreads();
    int v = (t < BKT_SIZE) ? cnt[t] : 0;
    if (t < BKT_SIZE) sc[t] = v;
    __syncthreads();
    for (int off = 1; off < BKT_SIZE; off <<= 1) {
        int a = (t < BKT_SIZE && t >= off) ? sc[t - off] : 0;
        __syncthreads();
        if (t < BKT_SIZE) sc[t] += a;
        __syncthreads();
    }
    if (t < BKT_SIZE) {
        int g = b * BKT_SIZE + t;
        if (g < N_NODES) {
            rowptr[g] = beg + sc[t] - v;          // begin pointer
            dinv[g] = rsqrtf((float)v + 1.0f);    // +1 self loop
        }
    }
    if (b == 0 && t == 0) rowptr[N_NODES] = N_EDGES;
}

// ------------------------------------------- m1s = bf16((x @ W1) * dinv)
// MFMA, W1 frags in LDS, register ring distance-6 A prefetch, no in-loop
// barriers (R9/R10 structure, verified).
#define G1_NBLK 1563   // ceil(100000/64)

__device__ inline void split8(const float4 a, const float4 b, short8v& hi, short8v& lo) {
    float f[8] = {a.x, a.y, a.z, a.w, b.x, b.y, b.z, b.w};
#pragma unroll
    for (int i = 0; i < 8; ++i) {
        unsigned int u = __float_as_uint(f[i]);
        unsigned int uh = u & 0xFFFF0000u;
        hi[i] = (short)(u >> 16);
        lo[i] = (short)f2bf(f[i] - __uint_as_float(uh));
    }
}

__global__ __launch_bounds__(256) void gemm1(const float* __restrict__ x,
        const uint4* __restrict__ wp, const float* __restrict__ dinv,
        unsigned short* __restrict__ m1s) {
    __shared__ uint4 swp[2048];   // 32 KB: all W1 frags (hi 0..1023, lo 1024..2047)
    const int t = threadIdx.x, b = blockIdx.x;
    const int lane = t & 63, w = t >> 6;
#pragma unroll
    for (int i = 0; i < 8; ++i) swp[i * 256 + t] = wp[i * 256 + t];
    __syncthreads();

    const int r16 = lane & 15, g = lane >> 4;
    const int rowbase = b * 64 + w * 16;
    const int row = rowbase + r16;
    const int srow = (row < N_NODES) ? row : 0;
    const float* pA = x + (size_t)srow * N_FEAT + g * 8;
    // tail step 15 (k=480..511): load valid iff last float < 500; else x[0] (B=0 there)
    const float* t0 = (g <= 2) ? pA + 480 : x;
    const float* t1 = (g <= 1) ? pA + 484 : x;

    // register ring, distance-6 prefetch (named slots, compile-time indices)
    float4 a0_0 = *(const float4*)(pA);        float4 a1_0 = *(const float4*)(pA + 4);
    float4 a0_1 = *(const float4*)(pA + 32);   float4 a1_1 = *(const float4*)(pA + 36);
    float4 a0_2 = *(const float4*)(pA + 64);   float4 a1_2 = *(const float4*)(pA + 68);
    float4 a0_3 = *(const float4*)(pA + 96);   float4 a1_3 = *(const float4*)(pA + 100);
    float4 a0_4 = *(const float4*)(pA + 128);  float4 a1_4 = *(const float4*)(pA + 132);
    float4 a0_5 = *(const float4*)(pA + 160);  float4 a1_5 = *(const float4*)(pA + 164);

    f32x4v acc = {0.f, 0.f, 0.f, 0.f};
#pragma unroll
    for (int s = 0; s < 16; ++s) {
        float4 xa, xb;
        switch (s % 6) {
            case 0: xa = a0_0; xb = a1_0; break;
            case 1: xa = a0_1; xb = a1_1; break;
            case 2: xa = a0_2; xb = a1_2; break;
            case 3: xa = a0_3; xb = a1_3; break;
            case 4: xa = a0_4; xb = a1_4; break;
            default: xa = a0_5; xb = a1_5; break;
        }
        if (s <= 9) {   // prefetch step s+6 into the slot just consumed
            int tg = s + 6;
            const float* p = (tg == 15) ? t0 : pA + tg * 32;
            const float* q = (tg == 15) ? t1 : pA + tg * 32 + 4;
            float4 n0 = *(const float4*)p;
            float4 n1 = *(const float4*)q;
            switch (s % 6) {
                case 0: a0_0 = n0; a1_0 = n1; break;
                case 1: a0_1 = n0; a1_1 = n1; break;
                case 2: a0_2 = n0; a1_2 = n1; break;
                case 3: a0_3 = n0; a1_3 = n1; break;
                case 4: a0_4 = n0; a1_4 = n1; break;
                default: a0_5 = n0; a1_5 = n1; break;
            }
        }
        short8v ah, al;
        split8(xa, xb, ah, al);
        short8v bh = *reinterpret_cast<const short8v*>(&swp[s * 64 + lane]);
        short8v bl = *reinterpret_cast<const short8v*>(&swp[1024 + s * 64 + lane]);
        acc = __builtin_amdgcn_mfma_f32_16x16x32_bf16(ah, bh, acc, 0, 0, 0);
        acc = __builtin_amdgcn_mfma_f32_16x16x32_bf16(al, bh, acc, 0, 0, 0);
        acc = __builtin_amdgcn_mfma_f32_16x16x32_bf16(ah, bl, acc, 0, 0, 0);
    }

    // C/D layout: col = lane&15, row = (lane>>4)*4 + j
#pragma unroll
    for (int j = 0; j < 4; ++j) {
        int r = rowbase + g * 4 + j;
        if (r < N_NODES) m1s[(size_t)r * 16 + r16] = f2bf(acc[j] * dinv[r]);
    }
}

// ---------------- pass 3b: scatter into LDS sbuf -> write sorted (for agg2)
// -> FUSED layer-1 aggregate from sbuf + bias + ReLU + h@W2 -> m2s.
__global__ __launch_bounds__(512) void sortAgg1(const unsigned int* __restrict__ binned,
        const int* __restrict__ bsum,
        const int* __restrict__ rowptr, const float* __restrict__ dinv,
        const unsigned short* __restrict__ m1s, const float* __restrict__ b1,
        const float* __restrict__ W2, unsigned int* __restrict__ sorted,
        unsigned short* __restrict__ m2s) {
    __shared__ unsigned int sbuf[SBUF_CAP];
    __shared__ int cur[BKT_SIZE];
    __shared__ float acc[BKT_SIZE * 17];
    __shared__ float sW2[N_HID * N_CLS];
    __shared__ float sb1[N_HID];
    int t = threadIdx.x, b = blockIdx.x;
    if (t < N_HID * N_CLS) sW2[t] = W2[t];
    if (t < N_HID) sb1[t] = b1[t];
    int beg = bsum[b];
    int end = (b < NBKT - 1) ? bsum[b + 1] : N_EDGES;
    if (t < BKT_SIZE) {
        int g = b * BKT_SIZE + t;
        cur[t] = ((g < N_NODES) ? rowptr[g] : end) - beg;   // bucket-local excl.
    }
    __syncthreads();
    for (int e = beg + t; e < end; e += 512) {
        unsigned int u = binned[e];
        int pos = atomicAdd(&cur[(u >> 17) & (BKT_SIZE - 1)], 1);
        if (pos < SBUF_CAP) sbuf[pos] = u & 0x1FFFF;
    }
    __syncthreads();
    int n = end - beg;
    for (int i = t; i < n; i += 512) sorted[beg + i] = sbuf[i];
    // ---- aggregate straight from sbuf (edge list stays in LDS)
    {
        int nn = t >> 2, q = t & 3;
        int g = b * BKT_SIZE + nn;
        float a0 = 0.f, a1 = 0.f, a2 = 0.f, a3 = 0.f;
        if (g < N_NODES) {
            int lbeg = rowptr[g] - beg;
            int lend = ((g + 1 <= N_NODES) ? rowptr[g + 1] : N_EDGES) - beg;
            int p = lbeg;
            for (; p + 3 < lend; p += 4) {
                unsigned int s0 = sbuf[p], s1 = sbuf[p + 1];
                unsigned int s2 = sbuf[p + 2], s3 = sbuf[p + 3];
                uint2 w0 = *(const uint2*)&m1s[(size_t)s0 * 16 + q * 4];
                uint2 w1 = *(const uint2*)&m1s[(size_t)s1 * 16 + q * 4];
                uint2 w2 = *(const uint2*)&m1s[(size_t)s2 * 16 + q * 4];
                uint2 w3 = *(const uint2*)&m1s[(size_t)s3 * 16 + q * 4];
                a0 += __uint_as_float(w0.x << 16);
                a1 += __uint_as_float(w0.x & 0xFFFF0000u);
                a2 += __uint_as_float(w0.y << 16);
                a3 += __uint_as_float(w0.y & 0xFFFF0000u);
                a0 += __uint_as_float(w1.x << 16);
                a1 += __uint_as_float(w1.x & 0xFFFF0000u);
                a2 += __uint_as_float(w1.y << 16);
                a3 += __uint_as_float(w1.y & 0xFFFF0000u);
                a0 += __uint_as_float(w2.x << 16);
                a1 += __uint_as_float(w2.x & 0xFFFF0000u);
                a2 += __uint_as_float(w2.y << 16);
                a3 += __uint_as_float(w2.y & 0xFFFF0000u);
                a0 += __uint_as_float(w3.x << 16);
                a1 += __uint_as_float(w3.x & 0xFFFF0000u);
                a2 += __uint_as_float(w3.y << 16);
                a3 += __uint_as_float(w3.y & 0xFFFF0000u);
            }
            for (; p < lend; ++p) {
                unsigned int s0 = sbuf[p];
                uint2 w0 = *(const uint2*)&m1s[(size_t)s0 * 16 + q * 4];
                a0 += __uint_as_float(w0.x << 16);
                a1 += __uint_as_float(w0.x & 0xFFFF0000u);
                a2 += __uint_as_float(w0.y << 16);
                a3 += __uint_as_float(w0.y & 0xFFFF0000u);
            }
        }
        __syncthreads();
        float* ap = &acc[nn * 17 + q * 4];
        ap[0] = a0; ap[1] = a1; ap[2] = a2; ap[3] = a3;
    }
    __syncthreads();
    // h = relu(dinv_g * (acc + m1s_g) + b1), in place (stride 17)
    for (int idx = t; idx < BKT_SIZE * 16; idx += 512) {
        int nn = idx >> 4, jj = idx & 15;
        int gg = b * BKT_SIZE + nn;
        if (gg < N_NODES) {
            float di = dinv[gg];
            float hv = di * (acc[nn * 17 + jj] + bf2f(m1s[(size_t)gg * 16 + jj])) + sb1[jj];
            acc[nn * 17 + jj] = hv > 0.f ? hv : 0.f;
        }
    }
    __syncthreads();
    // m2s = bf16(dinv_g * (h @ W2)), stride 8, slot 7 = 0 pad
    for (int idx = t; idx < BKT_SIZE * 8; idx += 512) {
        int nn = idx >> 3, cc = idx & 7;
        int gg = b * BKT_SIZE + nn;
        if (gg < N_NODES) {
            float sum = 0.f;
            if (cc < N_CLS) {
#pragma unroll
                for (int jj = 0; jj < N_HID; ++jj) sum += acc[nn * 17 + jj] * sW2[jj * 7 + cc];
                sum *= dinv[gg];
            }
            m2s[(size_t)gg * 8 + cc] = f2bf(sum);
        }
    }
}

// -------- layer-2 aggregate + bias + log-softmax. 512 thr: 4 lanes/node,
// lane q owns slots 2q..2q+1; sorted read via aligned uint4 (4 edges/load).
__global__ __launch_bounds__(512) void agg2(const unsigned int* __restrict__ sorted,
        const int* __restrict__ rowptr, const float* __restrict__ dinv,
        const unsigned short* __restrict__ m2s, const float* __restrict__ b2,
        float* __restrict__ out) {
    __shared__ float acc[BKT_SIZE * 9];
    int t = threadIdx.x, b = blockIdx.x;
    int n = t >> 2, q = t & 3;
    int g = b * BKT_SIZE + n;
    float a0 = 0.f, a1 = 0.f;
    if (g < N_NODES) {
        int beg = rowptr[g], end = rowptr[g + 1];
        int p = beg;
        for (; (p & 3) && p < end; ++p) {          // align to 16B
            unsigned int s0 = sorted[p];
            unsigned int w0 = *(const unsigned int*)&m2s[(size_t)s0 * 8 + q * 2];
            a0 += __uint_as_float(w0 << 16); a1 += __uint_as_float(w0 & 0xFFFF0000u);
        }
        for (; p + 3 < end; p += 4) {
            uint4 sv = *(const uint4*)&sorted[p];
            unsigned int w0 = *(const unsigned int*)&m2s[(size_t)sv.x * 8 + q * 2];
            unsigned int w1 = *(const unsigned int*)&m2s[(size_t)sv.y * 8 + q * 2];
            unsigned int w2 = *(const unsigned int*)&m2s[(size_t)sv.z * 8 + q * 2];
            unsigned int w3 = *(const unsigned int*)&m2s[(size_t)sv.w * 8 + q * 2];
            a0 += __uint_as_float(w0 << 16); a1 += __uint_as_float(w0 & 0xFFFF0000u);
            a0 += __uint_as_float(w1 << 16); a1 += __uint_as_float(w1 & 0xFFFF0000u);
            a0 += __uint_as_float(w2 << 16); a1 += __uint_as_float(w2 & 0xFFFF0000u);
            a0 += __uint_as_float(w3 << 16); a1 += __uint_as_float(w3 & 0xFFFF0000u);
        }
        for (; p < end; ++p) {
            unsigned int s0 = sorted[p];
            unsigned int w0 = *(const unsigned int*)&m2s[(size_t)s0 * 8 + q * 2];
            a0 += __uint_as_float(w0 << 16); a1 += __uint_as_float(w0 & 0xFFFF0000u);
        }
    }
    float* ap = &acc[n * 9 + q * 2];
    ap[0] = a0; ap[1] = a1;
    __syncthreads();
    int j = t & 7;
    for (int pass = 0; pass < 2; ++pass) {
        int nn = (t >> 3) + pass * 64;
        int gg = b * BKT_SIZE + nn;
        bool valid = (gg < N_NODES) && (j < N_CLS);
        float v = -1e30f;
        if (valid) {
            float di = dinv[gg];
            v = di * (acc[nn * 9 + j] + bf2f(m2s[(size_t)gg * 8 + j])) + b2[j];
        }
        float mx = v;
#pragma unroll
        for (int off = 1; off < 8; off <<= 1) mx = fmaxf(mx, __shfl_xor(mx, off, 8));
        float ex = valid ? expf(v - mx) : 0.f;
        float sum = ex;
#pragma unroll
        for (int off = 1; off < 8; off <<= 1) sum += __shfl_xor(sum, off, 8);
        float ls = mx + logf(sum);
        if (valid) out[(size_t)gg * 7 + j] = v - ls;
    }
}

// ----------------------------------------------------------------
extern "C" void kernel_launch(void* const* d_in, const int* in_sizes, int n_in,
                              void* d_out, int out_size, void* d_ws, size_t ws_size,
                              hipStream_t stream) {
    const float* x  = (const float*)d_in[0];
    const int*   ei = (const int*)d_in[1];
    const float* W1 = (const float*)d_in[2];
    const float* b1 = (const float*)d_in[3];
    const float* W2 = (const float*)d_in[4];
    const float* b2 = (const float*)d_in[5];
    float* out = (float*)d_out;
    char*  wsb = (char*)d_ws;   // needs ~32 MB

    const int* src = ei;               // edge_index[0]
    const int* dst = ei + N_EDGES;     // edge_index[1]

    float*          dinv   = (float*)wsb + OFF_DINV;
    int*            counts = (int*)wsb + OFF_COUNTS;
    int*            bsum   = (int*)wsb + OFF_BSUM;
    int*            rowptr = (int*)wsb + OFF_ROWP;
    unsigned int*   binned = (unsigned int*)wsb + OFF_BINNED;
    unsigned int*   sorted = (unsigned int*)wsb + OFF_SORTED;
    uint4*          wp     = (uint4*)((int*)wsb + OFF_WP);
    unsigned short* m1s    = (unsigned short*)(wsb + (size_t)OFF_M1S * 4);
    unsigned short* m2s    = (unsigned short*)(wsb + (size_t)OFF_M2S * 4);

    hist       <<<NBLK_BIN, 1024, 0, stream>>>(dst, counts);
    scanA      <<<NBLK_SCANA, 256, 0, stream>>>(counts, bsum);
    scanB_wpack<<<1, 1024, 0, stream>>>(bsum, W1, wp);
    binpass    <<<NBLK_BIN, 1024, 0, stream>>>(src, dst, counts, bsum, binned);
    sortA      <<<NBKT, 512, 0, stream>>>(binned, bsum, rowptr, dinv);
    gemm1      <<<G1_NBLK, 256, 0, stream>>>(x, wp, dinv, m1s);
    sortAgg1   <<<NBKT, 512, 0, stream>>>(binned, bsum, rowptr, dinv,
                                          m1s, b1, W2, sorted, m2s);
    agg2       <<<NBKT, 512, 0, stream>>>(sorted, rowptr, dinv, m2s, b2, out);
}

// Round 13
// 415.736 us; speedup vs baseline: 1.0282x; 1.0059x over previous
//
#include <hip/hip_runtime.h>
#include <math.h>

#define N_NODES 100000
#define N_EDGES 3200000
#define N_FEAT  500
#define N_HID   16
#define N_CLS   7

#define BKT_SHIFT 7
#define BKT_SIZE  128
#define NBKT      782            // ceil(100000/128)
#define NBLK_BIN  256            // edge-chunk blocks for hist/binpass
#define EDGES_PER_BLK 12500      // 256 * 12500 = 3.2M exactly
#define COUNTS_LEN (NBKT * NBLK_BIN)   // 200192
#define NBLK_SCANA NBKT          // scanA: one block per bucket
#define SBUF_CAP  5632           // max edges/bucket (mean 4092, sd 64 -> 24 sd)

// ---------------- workspace layout (dword offsets) --------------------------
// counts layout: C[block][bucket] = counts[block*NBKT + bucket]
#define OFF_DINV   0            // 100000 f
#define OFF_COUNTS 100000       // 200192 i
#define OFF_BSUM   300192       // 1024 i
#define OFF_ROWP   301216       // 100001 i (+3 pad)
#define OFF_BINNED 401220       // 3200000 u32 (src | dst_local<<17)
#define OFF_SORTED 3601220      // 3200000 u32 (src, grouped per dst node)
#define OFF_WP     6801220      // 8192 dwords packed W1
#define OFF_M1S    6809412      // 800000 dwords = 1.6M ushort bf16 (m1*dinv)
#define OFF_M2S    7609412      // 400000 dwords = 800K ushort bf16 (m2*dinv)
// total ~32.0 MB

typedef __attribute__((ext_vector_type(8))) short short8v;
typedef __attribute__((ext_vector_type(4))) float f32x4v;

// ------------------------------------------------------------- bf16 helpers
__device__ inline unsigned short f2bf(float f) {
    unsigned int u = __float_as_uint(f);
    return (unsigned short)((u + 0x7FFF + ((u >> 16) & 1)) >> 16);
}
__device__ inline float bf2f(unsigned short h) {
    return __uint_as_float((unsigned int)h << 16);
}

// ------------------------------------------------------------- pass 1: hist
__global__ __launch_bounds__(1024) void hist(const int* __restrict__ dst,
                                             int* __restrict__ counts) {
    __shared__ int cnt[4][NBKT];
    int t = threadIdx.x, b = blockIdx.x;
    int wq = (t >> 6) & 3;
    for (int i = t; i < 4 * NBKT; i += 1024) ((int*)cnt)[i] = 0;
    __syncthreads();
    const int4* d4 = (const int4*)(dst + b * EDGES_PER_BLK);
    for (int k = t; k < EDGES_PER_BLK / 4; k += 1024) {
        int4 d = d4[k];
        atomicAdd(&cnt[wq][d.x >> BKT_SHIFT], 1);
        atomicAdd(&cnt[wq][d.y >> BKT_SHIFT], 1);
        atomicAdd(&cnt[wq][d.z >> BKT_SHIFT], 1);
        atomicAdd(&cnt[wq][d.w >> BKT_SHIFT], 1);
    }
    __syncthreads();
    for (int i = t; i < NBKT; i += 1024)
        counts[b * NBKT + i] = cnt[0][i] + cnt[1][i] + cnt[2][i] + cnt[3][i];
}

// ---------------- scanA: block k scans bucket k across the 256 bin-blocks
__global__ void scanA(int* __restrict__ counts, int* __restrict__ bsum) {
    __shared__ int s[256];
    int t = threadIdx.x, k = blockIdx.x;
    int v = counts[t * NBKT + k];
    s[t] = v;
    __syncthreads();
    for (int off = 1; off < 256; off <<= 1) {
        int a = (t >= off) ? s[t - off] : 0;
        __syncthreads();
        s[t] += a;
        __syncthreads();
    }
    counts[t * NBKT + k] = s[t] - v;   // exclusive within bucket k
    if (t == 255) bsum[k] = s[255];    // bucket total
}

// scanB fused with wpack (both are exactly 1024 independent threads of work)
__global__ void scanB_wpack(int* __restrict__ bsum, const float* __restrict__ W1,
                            uint4* __restrict__ wp) {
    int t = threadIdx.x;
    {
        int p = t;
        int s = p >> 6, l = p & 63;
        int col = l & 15, kb = s * 32 + (l >> 4) * 8;
        unsigned int hw[4], lw[4];
#pragma unroll
        for (int d = 0; d < 4; ++d) {
            unsigned int hpair = 0, lpair = 0;
#pragma unroll
            for (int e = 0; e < 2; ++e) {
                int k = kb + d * 2 + e;
                float w0 = (k < N_FEAT) ? W1[k * 16 + col] : 0.f;
                unsigned int u = __float_as_uint(w0);
                unsigned int uh = u & 0xFFFF0000u;        // hi = truncated bf16
                float res = w0 - __uint_as_float(uh);     // exact residual
                hpair |= (uh >> 16) << (16 * e);
                lpair |= (unsigned int)f2bf(res) << (16 * e);
            }
            hw[d] = hpair; lw[d] = lpair;
        }
        wp[p] = make_uint4(hw[0], hw[1], hw[2], hw[3]);
        wp[1024 + p] = make_uint4(lw[0], lw[1], lw[2], lw[3]);
    }
    __shared__ int s[1024];
    int v = (t < NBKT) ? bsum[t] : 0;
    s[t] = v;
    __syncthreads();
    for (int off = 1; off < 1024; off <<= 1) {
        int a = (t >= off) ? s[t - off] : 0;
        __syncthreads();
        s[t] += a;
        __syncthreads();
    }
    if (t < NBKT) bsum[t] = s[t] - v;
}

// ------------------------------------------------------------- pass 2: bin
__global__ __launch_bounds__(1024) void binpass(const int* __restrict__ src,
                        const int* __restrict__ dst,
                        const int* __restrict__ counts, const int* __restrict__ bsum,
                        unsigned int* __restrict__ binned) {
    __shared__ int cur[NBKT];
    int t = threadIdx.x, b = blockIdx.x;
    for (int i = t; i < NBKT; i += 1024) cur[i] = counts[b * NBKT + i] + bsum[i];
    __syncthreads();
    const int4* s4 = (const int4*)(src + b * EDGES_PER_BLK);
    const int4* d4 = (const int4*)(dst + b * EDGES_PER_BLK);
    for (int k = t; k < EDGES_PER_BLK / 4; k += 1024) {
        int4 d = d4[k];
        int4 s = s4[k];
        int pos;
        pos = atomicAdd(&cur[d.x >> BKT_SHIFT], 1);
        binned[pos] = (unsigned int)s.x | ((unsigned int)(d.x & (BKT_SIZE - 1)) << 17);
        pos = atomicAdd(&cur[d.y >> BKT_SHIFT], 1);
        binned[pos] = (unsigned int)s.y | ((unsigned int)(d.y & (BKT_SIZE - 1)) << 17);
        pos = atomicAdd(&cur[d.z >> BKT_SHIFT], 1);
        binned[pos] = (unsigned int)s.z | ((unsigned int)(d.z & (BKT_SIZE - 1)) << 17);
        pos = atomicAdd(&cur[d.w >> BKT_SHIFT], 1);
        binned[pos] = (unsigned int)s.w | ((unsigned int)(d.w & (BKT_SIZE - 1)) << 17);
    }
}

// ---------------- pass 3a: per-node histogram -> rowptr (begin) + dinv
__global__ __launch_bounds__(512) void sortA(const unsigned int* __restrict__ binned,
        const int* __restrict__ bsum,
        int* __restrict__ rowptr, float* __restrict__ dinv) {
    __shared__ int cnt[BKT_SIZE];
    __shared__ int sc[BKT_SIZE];
    int t = threadIdx.x, b = blockIdx.x;
    int beg = bsum[b];
    int end = (b < NBKT - 1) ? bsum[b + 1] : N_EDGES;
    if (t < BKT_SIZE) cnt[t] = 0;
    __syncthreads();
    for (int e = beg + t; e < end; e += 512)
        atomicAdd(&cnt[(binned[e] >> 17) & (BKT_SIZE - 1)], 1);
    __syncthreads();
    int v = (t < BKT_SIZE) ? cnt[t] : 0;
    if (t < BKT_SIZE) sc[t] = v;
    __syncthreads();
    for (int off = 1; off < BKT_SIZE; off <<= 1) {
        int a = (t < BKT_SIZE && t >= off) ? sc[t - off] : 0;
        __syncthreads();
        if (t < BKT_SIZE) sc[t] += a;
        __syncthreads();
    }
    if (t < BKT_SIZE) {
        int g = b * BKT_SIZE + t;
        if (g < N_NODES) {
            rowptr[g] = beg + sc[t] - v;          // begin pointer
            dinv[g] = rsqrtf((float)v + 1.0f);    // +1 self loop
        }
    }
    if (b == 0 && t == 0) rowptr[N_NODES] = N_EDGES;
}

// ------------------------------------------- m1s = bf16((x @ W1) * dinv)
// MFMA, W1 frags in LDS, register ring distance-6 A prefetch, no in-loop
// barriers (R9/R10 structure, verified).
#define G1_NBLK 1563   // ceil(100000/64)

__device__ inline void split8(const float4 a, const float4 b, short8v& hi, short8v& lo) {
    float f[8] = {a.x, a.y, a.z, a.w, b.x, b.y, b.z, b.w};
#pragma unroll
    for (int i = 0; i < 8; ++i) {
        unsigned int u = __float_as_uint(f[i]);
        unsigned int uh = u & 0xFFFF0000u;
        hi[i] = (short)(u >> 16);
        lo[i] = (short)f2bf(f[i] - __uint_as_float(uh));
    }
}

__global__ __launch_bounds__(256) void gemm1(const float* __restrict__ x,
        const uint4* __restrict__ wp, const float* __restrict__ dinv,
        unsigned short* __restrict__ m1s) {
    __shared__ uint4 swp[2048];   // 32 KB: all W1 frags (hi 0..1023, lo 1024..2047)
    const int t = threadIdx.x, b = blockIdx.x;
    const int lane = t & 63, w = t >> 6;
#pragma unroll
    for (int i = 0; i < 8; ++i) swp[i * 256 + t] = wp[i * 256 + t];
    __syncthreads();

    const int r16 = lane & 15, g = lane >> 4;
    const int rowbase = b * 64 + w * 16;
    const int row = rowbase + r16;
    const int srow = (row < N_NODES) ? row : 0;
    const float* pA = x + (size_t)srow * N_FEAT + g * 8;
    const float* t0 = (g <= 2) ? pA + 480 : x;
    const float* t1 = (g <= 1) ? pA + 484 : x;

    float4 a0_0 = *(const float4*)(pA);        float4 a1_0 = *(const float4*)(pA + 4);
    float4 a0_1 = *(const float4*)(pA + 32);   float4 a1_1 = *(const float4*)(pA + 36);
    float4 a0_2 = *(const float4*)(pA + 64);   float4 a1_2 = *(const float4*)(pA + 68);
    float4 a0_3 = *(const float4*)(pA + 96);   float4 a1_3 = *(const float4*)(pA + 100);
    float4 a0_4 = *(const float4*)(pA + 128);  float4 a1_4 = *(const float4*)(pA + 132);
    float4 a0_5 = *(const float4*)(pA + 160);  float4 a1_5 = *(const float4*)(pA + 164);

    f32x4v acc = {0.f, 0.f, 0.f, 0.f};
#pragma unroll
    for (int s = 0; s < 16; ++s) {
        float4 xa, xb;
        switch (s % 6) {
            case 0: xa = a0_0; xb = a1_0; break;
            case 1: xa = a0_1; xb = a1_1; break;
            case 2: xa = a0_2; xb = a1_2; break;
            case 3: xa = a0_3; xb = a1_3; break;
            case 4: xa = a0_4; xb = a1_4; break;
            default: xa = a0_5; xb = a1_5; break;
        }
        if (s <= 9) {
            int tg = s + 6;
            const float* p = (tg == 15) ? t0 : pA + tg * 32;
            const float* q = (tg == 15) ? t1 : pA + tg * 32 + 4;
            float4 n0 = *(const float4*)p;
            float4 n1 = *(const float4*)q;
            switch (s % 6) {
                case 0: a0_0 = n0; a1_0 = n1; break;
                case 1: a0_1 = n0; a1_1 = n1; break;
                case 2: a0_2 = n0; a1_2 = n1; break;
                case 3: a0_3 = n0; a1_3 = n1; break;
                case 4: a0_4 = n0; a1_4 = n1; break;
                default: a0_5 = n0; a1_5 = n1; break;
            }
        }
        short8v ah, al;
        split8(xa, xb, ah, al);
        short8v bh = *reinterpret_cast<const short8v*>(&swp[s * 64 + lane]);
        short8v bl = *reinterpret_cast<const short8v*>(&swp[1024 + s * 64 + lane]);
        acc = __builtin_amdgcn_mfma_f32_16x16x32_bf16(ah, bh, acc, 0, 0, 0);
        acc = __builtin_amdgcn_mfma_f32_16x16x32_bf16(al, bh, acc, 0, 0, 0);
        acc = __builtin_amdgcn_mfma_f32_16x16x32_bf16(ah, bl, acc, 0, 0, 0);
    }

#pragma unroll
    for (int j = 0; j < 4; ++j) {
        int r = rowbase + g * 4 + j;
        if (r < N_NODES) m1s[(size_t)r * 16 + r16] = f2bf(acc[j] * dinv[r]);
    }
}

// ---------------- pass 3b: scatter into LDS sbuf -> write sorted (for agg2)
// -> FUSED layer-1 aggregate + bias + ReLU + h@W2 -> m2s.
// 1024 thr; aggregate uses 8 lanes/node: half h (lanes 0-3 / 4-7) walks
// edges lbeg+h, lbeg+h+2, ... (4-unrolled) -> serial depth halved; halves
// combined through acc[2][.] in LDS. Per-edge gather bytes unchanged.
__global__ __launch_bounds__(1024) void sortAgg1(const unsigned int* __restrict__ binned,
        const int* __restrict__ bsum,
        const int* __restrict__ rowptr, const float* __restrict__ dinv,
        const unsigned short* __restrict__ m1s, const float* __restrict__ b1,
        const float* __restrict__ W2, unsigned int* __restrict__ sorted,
        unsigned short* __restrict__ m2s) {
    __shared__ unsigned int sbuf[SBUF_CAP];
    __shared__ int cur[BKT_SIZE];
    __shared__ float acc[2][BKT_SIZE * 17];
    __shared__ float sW2[N_HID * N_CLS];
    __shared__ float sb1[N_HID];
    int t = threadIdx.x, b = blockIdx.x;
    if (t < N_HID * N_CLS) sW2[t] = W2[t];
    if (t < N_HID) sb1[t] = b1[t];
    int beg = bsum[b];
    int end = (b < NBKT - 1) ? bsum[b + 1] : N_EDGES;
    if (t < BKT_SIZE) {
        int g = b * BKT_SIZE + t;
        cur[t] = ((g < N_NODES) ? rowptr[g] : end) - beg;   // bucket-local excl.
    }
    __syncthreads();
    for (int e = beg + t; e < end; e += 1024) {
        unsigned int u = binned[e];
        int pos = atomicAdd(&cur[(u >> 17) & (BKT_SIZE - 1)], 1);
        if (pos < SBUF_CAP) sbuf[pos] = u & 0x1FFFF;
    }
    __syncthreads();
    int n = end - beg;
    for (int i = t; i < n; i += 1024) sorted[beg + i] = sbuf[i];
    // ---- aggregate straight from sbuf: 8 lanes/node, split-walk halves
    {
        int nn = t >> 3, q8 = t & 7;
        int half = q8 >> 2, q = q8 & 3;
        int g = b * BKT_SIZE + nn;
        float a0 = 0.f, a1 = 0.f, a2 = 0.f, a3 = 0.f;
        if (g < N_NODES) {
            int lbeg = rowptr[g] - beg;
            int lend = rowptr[g + 1] - beg;
            int p = lbeg + half;
            for (; p + 6 < lend; p += 8) {
                unsigned int s0 = sbuf[p],     s1 = sbuf[p + 2];
                unsigned int s2 = sbuf[p + 4], s3 = sbuf[p + 6];
                uint2 w0 = *(const uint2*)&m1s[(size_t)s0 * 16 + q * 4];
                uint2 w1 = *(const uint2*)&m1s[(size_t)s1 * 16 + q * 4];
                uint2 w2 = *(const uint2*)&m1s[(size_t)s2 * 16 + q * 4];
                uint2 w3 = *(const uint2*)&m1s[(size_t)s3 * 16 + q * 4];
                a0 += __uint_as_float(w0.x << 16);
                a1 += __uint_as_float(w0.x & 0xFFFF0000u);
                a2 += __uint_as_float(w0.y << 16);
                a3 += __uint_as_float(w0.y & 0xFFFF0000u);
                a0 += __uint_as_float(w1.x << 16);
                a1 += __uint_as_float(w1.x & 0xFFFF0000u);
                a2 += __uint_as_float(w1.y << 16);
                a3 += __uint_as_float(w1.y & 0xFFFF0000u);
                a0 += __uint_as_float(w2.x << 16);
                a1 += __uint_as_float(w2.x & 0xFFFF0000u);
                a2 += __uint_as_float(w2.y << 16);
                a3 += __uint_as_float(w2.y & 0xFFFF0000u);
                a0 += __uint_as_float(w3.x << 16);
                a1 += __uint_as_float(w3.x & 0xFFFF0000u);
                a2 += __uint_as_float(w3.y << 16);
                a3 += __uint_as_float(w3.y & 0xFFFF0000u);
            }
            for (; p < lend; p += 2) {
                unsigned int s0 = sbuf[p];
                uint2 w0 = *(const uint2*)&m1s[(size_t)s0 * 16 + q * 4];
                a0 += __uint_as_float(w0.x << 16);
                a1 += __uint_as_float(w0.x & 0xFFFF0000u);
                a2 += __uint_as_float(w0.y << 16);
                a3 += __uint_as_float(w0.y & 0xFFFF0000u);
            }
        }
        float* ap = &acc[half][nn * 17 + q * 4];
        ap[0] = a0; ap[1] = a1; ap[2] = a2; ap[3] = a3;
    }
    __syncthreads();
    // h = relu(dinv_g * (accE + accO + m1s_g) + b1) -> acc[0] (stride 17)
    for (int idx = t; idx < BKT_SIZE * 16; idx += 1024) {
        int nn = idx >> 4, jj = idx & 15;
        int gg = b * BKT_SIZE + nn;
        if (gg < N_NODES) {
            float di = dinv[gg];
            float hv = di * (acc[0][nn * 17 + jj] + acc[1][nn * 17 + jj]
                             + bf2f(m1s[(size_t)gg * 16 + jj])) + sb1[jj];
            acc[0][nn * 17 + jj] = hv > 0.f ? hv : 0.f;
        }
    }
    __syncthreads();
    // m2s = bf16(dinv_g * (h @ W2)), stride 8, slot 7 = 0 pad
    for (int idx = t; idx < BKT_SIZE * 8; idx += 1024) {
        int nn = idx >> 3, cc = idx & 7;
        int gg = b * BKT_SIZE + nn;
        if (gg < N_NODES) {
            float sum = 0.f;
            if (cc < N_CLS) {
#pragma unroll
                for (int jj = 0; jj < N_HID; ++jj) sum += acc[0][nn * 17 + jj] * sW2[jj * 7 + cc];
                sum *= dinv[gg];
            }
            m2s[(size_t)gg * 8 + cc] = f2bf(sum);
        }
    }
}

// -------- layer-2 aggregate + bias + log-softmax. 1024 thr: 8 lanes/node
// (half h walks edges beg+h, +2, ..., 4-unrolled); halves combined in LDS.
__global__ __launch_bounds__(1024) void agg2(const unsigned int* __restrict__ sorted,
        const int* __restrict__ rowptr, const float* __restrict__ dinv,
        const unsigned short* __restrict__ m2s, const float* __restrict__ b2,
        float* __restrict__ out) {
    __shared__ float acc[2][BKT_SIZE * 9];
    int t = threadIdx.x, b = blockIdx.x;
    int nn = t >> 3, q8 = t & 7;
    int half = q8 >> 2, q = q8 & 3;
    int g = b * BKT_SIZE + nn;
    float a0 = 0.f, a1 = 0.f;
    if (g < N_NODES) {
        int beg = rowptr[g], end = rowptr[g + 1];
        int p = beg + half;
        for (; p + 6 < end; p += 8) {
            unsigned int s0 = sorted[p],     s1 = sorted[p + 2];
            unsigned int s2 = sorted[p + 4], s3 = sorted[p + 6];
            unsigned int w0 = *(const unsigned int*)&m2s[(size_t)s0 * 8 + q * 2];
            unsigned int w1 = *(const unsigned int*)&m2s[(size_t)s1 * 8 + q * 2];
            unsigned int w2 = *(const unsigned int*)&m2s[(size_t)s2 * 8 + q * 2];
            unsigned int w3 = *(const unsigned int*)&m2s[(size_t)s3 * 8 + q * 2];
            a0 += __uint_as_float(w0 << 16); a1 += __uint_as_float(w0 & 0xFFFF0000u);
            a0 += __uint_as_float(w1 << 16); a1 += __uint_as_float(w1 & 0xFFFF0000u);
            a0 += __uint_as_float(w2 << 16); a1 += __uint_as_float(w2 & 0xFFFF0000u);
            a0 += __uint_as_float(w3 << 16); a1 += __uint_as_float(w3 & 0xFFFF0000u);
        }
        for (; p < end; p += 2) {
            unsigned int s0 = sorted[p];
            unsigned int w0 = *(const unsigned int*)&m2s[(size_t)s0 * 8 + q * 2];
            a0 += __uint_as_float(w0 << 16); a1 += __uint_as_float(w0 & 0xFFFF0000u);
        }
    }
    float* ap = &acc[half][nn * 9 + q * 2];
    ap[0] = a0; ap[1] = a1;
    __syncthreads();
    // epilogue: 128 nodes x 8 j-lanes = 1024 threads, one pass
    int j = t & 7;
    int gg = b * BKT_SIZE + (t >> 3);
    bool valid = (gg < N_NODES) && (j < N_CLS);
    float v = -1e30f;
    if (valid) {
        float di = dinv[gg];
        v = di * (acc[0][(t >> 3) * 9 + j] + acc[1][(t >> 3) * 9 + j]
                  + bf2f(m2s[(size_t)gg * 8 + j])) + b2[j];
    }
    float mx = v;
#pragma unroll
    for (int off = 1; off < 8; off <<= 1) mx = fmaxf(mx, __shfl_xor(mx, off, 8));
    float ex = valid ? expf(v - mx) : 0.f;
    float sum = ex;
#pragma unroll
    for (int off = 1; off < 8; off <<= 1) sum += __shfl_xor(sum, off, 8);
    float ls = mx + logf(sum);
    if (valid) out[(size_t)gg * 7 + j] = v - ls;
}

// ----------------------------------------------------------------
extern "C" void kernel_launch(void* const* d_in, const int* in_sizes, int n_in,
                              void* d_out, int out_size, void* d_ws, size_t ws_size,
                              hipStream_t stream) {
    const float* x  = (const float*)d_in[0];
    const int*   ei = (const int*)d_in[1];
    const float* W1 = (const float*)d_in[2];
    const float* b1 = (const float*)d_in[3];
    const float* W2 = (const float*)d_in[4];
    const float* b2 = (const float*)d_in[5];
    float* out = (float*)d_out;
    char*  wsb = (char*)d_ws;   // needs ~32 MB

    const int* src = ei;               // edge_index[0]
    const int* dst = ei + N_EDGES;     // edge_index[1]

    float*          dinv   = (float*)wsb + OFF_DINV;
    int*            counts = (int*)wsb + OFF_COUNTS;
    int*            bsum   = (int*)wsb + OFF_BSUM;
    int*            rowptr = (int*)wsb + OFF_ROWP;
    unsigned int*   binned = (unsigned int*)wsb + OFF_BINNED;
    unsigned int*   sorted = (unsigned int*)wsb + OFF_SORTED;
    uint4*          wp     = (uint4*)((int*)wsb + OFF_WP);
    unsigned short* m1s    = (unsigned short*)(wsb + (size_t)OFF_M1S * 4);
    unsigned short* m2s    = (unsigned short*)(wsb + (size_t)OFF_M2S * 4);

    hist       <<<NBLK_BIN, 1024, 0, stream>>>(dst, counts);
    scanA      <<<NBLK_SCANA, 256, 0, stream>>>(counts, bsum);
    scanB_wpack<<<1, 1024, 0, stream>>>(bsum, W1, wp);
    binpass    <<<NBLK_BIN, 1024, 0, stream>>>(src, dst, counts, bsum, binned);
    sortA      <<<NBKT, 512, 0, stream>>>(binned, bsum, rowptr, dinv);
    gemm1      <<<G1_NBLK, 256, 0, stream>>>(x, wp, dinv, m1s);
    sortAgg1   <<<NBKT, 1024, 0, stream>>>(binned, bsum, rowptr, dinv,
                                           m1s, b1, W2, sorted, m2s);
    agg2       <<<NBKT, 1024, 0, stream>>>(sorted, rowptr, dinv, m2s, b2, out);
}